// Round 1
// baseline (28274.744 us; speedup 1.0000x reference)
//
#include <hip/hip_runtime.h>
#include <cmath>

// MessageDecoder: 20-step LSTM greedy decoder, B=32768, H=512, 65 actions.
// Strategy (round 1, f32-exact):
//  - precompute gates_x = emb @ W_ih^T + b_ih + b_hh  (67x2048 table -> gather)
//  - persistent kernel: 1 block = 32 batch rows through all 20 steps
//    h in LDS (stride-padded), c in registers, weights pre-transposed (k-major)
//  - VALU f32 matmul h @ W_hh^T: thread t owns h-col t, acc i/f/g/o for 32 rows

#define HH      512
#define G4      2048
#define NACTS   65
#define NVOCAB  67
#define MAXLEN  20
#define NB      32768
#define TM      32
#define NTH     512
#define EOS_TOK 0
#define PAD_TOK 65
#define BOS_TOK 66
#define HSTR    516   // LDS row stride (pad 4 floats: bank-conflict-free, 16B aligned)

__global__ void prep_gxa_kernel(const float* __restrict__ emb,
                                const float* __restrict__ W_ih,
                                const float* __restrict__ b_ih,
                                const float* __restrict__ b_hh,
                                float* __restrict__ gxa) {
  int id = blockIdx.x * blockDim.x + threadIdx.x;
  if (id >= NVOCAB * G4) return;
  int a = id / G4, c = id - a * G4;
  const float* e = emb + (size_t)a * HH;
  const float* w = W_ih + (size_t)c * HH;
  float acc = 0.f;
  for (int k = 0; k < HH; ++k) acc = fmaf(e[k], w[k], acc);
  gxa[id] = acc + b_ih[c] + b_hh[c];
}

// dst[cols][rows] = src[rows][cols]^T ; consecutive id -> coalesced dst write
__global__ void prep_T_kernel(const float* __restrict__ src, float* __restrict__ dst,
                              int rows, int cols) {
  int id = blockIdx.x * blockDim.x + threadIdx.x;
  if (id >= rows * cols) return;
  int c = id / rows, r = id - c * rows;
  dst[id] = src[(size_t)r * cols + c];
}

__global__ __launch_bounds__(NTH, 2)
void decode_kernel(const float* __restrict__ encoded,
                   const float* __restrict__ gxa,
                   const float* __restrict__ whhT,   // [512][2048] k-major
                   const float* __restrict__ wcT,    // [512][512]  k-major
                   const float* __restrict__ whT,    // [512][512]  k-major
                   const float* __restrict__ bc,
                   const float* __restrict__ bh,
                   const float* __restrict__ Wa,     // [65][512]
                   const float* __restrict__ ba,
                   float* __restrict__ out) {
  __shared__ float sh_h[TM][HSTR];         // current hidden state
  __shared__ float sh_buf[TM][HSTR];       // enc staging (prologue) / Wa staging (steps)
  __shared__ float sh_logits[TM][NACTS + 3];
  __shared__ int   sh_last[TM];
  __shared__ int   sh_stop[TM];
  __shared__ float sh_ent[TM];
  __shared__ int   sh_len[TM];

  const int t = threadIdx.x;               // owns h-column t
  const int row0 = blockIdx.x * TM;

  // ---- stage encoded[row0:row0+32][:] into sh_buf (coalesced float4) ----
  #pragma unroll
  for (int i = 0; i < (TM * HH / 4) / NTH; ++i) {
    int f4 = i * NTH + t;
    int idx = f4 * 4;
    int r = idx >> 9;
    int c = idx & (HH - 1);
    *reinterpret_cast<float4*>(&sh_buf[r][c]) =
        *reinterpret_cast<const float4*>(encoded + (size_t)(row0 + r) * HH + c);
  }
  if (t < TM) { sh_last[t] = BOS_TOK; sh_stop[t] = 0; sh_ent[t] = 0.f; sh_len[t] = 0; }
  __syncthreads();

  // ---- h0 = enc@Wc^T + bc ; c0 = enc@Wh^T + bh  (reference's intentional swap) ----
  float hacc[TM], cacc[TM];
  #pragma unroll
  for (int r = 0; r < TM; ++r) { hacc[r] = 0.f; cacc[r] = 0.f; }
  for (int k4 = 0; k4 < HH / 4; ++k4) {
    int k = k4 * 4;
    float wc0 = wcT[(size_t)(k + 0) * HH + t];
    float wc1 = wcT[(size_t)(k + 1) * HH + t];
    float wc2 = wcT[(size_t)(k + 2) * HH + t];
    float wc3 = wcT[(size_t)(k + 3) * HH + t];
    float wh0 = whT[(size_t)(k + 0) * HH + t];
    float wh1 = whT[(size_t)(k + 1) * HH + t];
    float wh2 = whT[(size_t)(k + 2) * HH + t];
    float wh3 = whT[(size_t)(k + 3) * HH + t];
    #pragma unroll
    for (int r = 0; r < TM; ++r) {
      float4 e = *reinterpret_cast<const float4*>(&sh_buf[r][k]);
      hacc[r] = fmaf(e.x, wc0, fmaf(e.y, wc1, fmaf(e.z, wc2, fmaf(e.w, wc3, hacc[r]))));
      cacc[r] = fmaf(e.x, wh0, fmaf(e.y, wh1, fmaf(e.z, wh2, fmaf(e.w, wh3, cacc[r]))));
    }
  }
  float cst[TM];
  {
    float bcv = bc[t], bhv = bh[t];
    #pragma unroll
    for (int r = 0; r < TM; ++r) {
      sh_h[r][t] = hacc[r] + bcv;
      cst[r] = cacc[r] + bhv;
    }
  }
  __syncthreads();

  // ---- 20 decode steps ----
  for (int step = 0; step < MAXLEN; ++step) {
    // gate init from precomputed x-side table (gather by last token)
    float ai[TM], af[TM], ag[TM], ao[TM];
    #pragma unroll
    for (int r = 0; r < TM; ++r) {
      const float* g = gxa + (size_t)sh_last[r] * G4;
      ai[r] = g[t];
      af[r] = g[HH + t];
      ag[r] = g[2 * HH + t];
      ao[r] = g[3 * HH + t];
    }
    // gates += h @ W_hh^T  (k-major weights, uniform-broadcast h from LDS)
    for (int k4 = 0; k4 < HH / 4; ++k4) {
      const float* wb = whhT + (size_t)k4 * 4 * G4 + t;
      float wi0 = wb[0],          wf0 = wb[HH],          wg0 = wb[2 * HH],          wo0 = wb[3 * HH];
      float wi1 = wb[G4],         wf1 = wb[G4 + HH],     wg1 = wb[G4 + 2 * HH],     wo1 = wb[G4 + 3 * HH];
      float wi2 = wb[2 * G4],     wf2 = wb[2 * G4 + HH], wg2 = wb[2 * G4 + 2 * HH], wo2 = wb[2 * G4 + 3 * HH];
      float wi3 = wb[3 * G4],     wf3 = wb[3 * G4 + HH], wg3 = wb[3 * G4 + 2 * HH], wo3 = wb[3 * G4 + 3 * HH];
      #pragma unroll
      for (int r = 0; r < TM; ++r) {
        float4 h4 = *reinterpret_cast<const float4*>(&sh_h[r][k4 * 4]);
        ai[r] = fmaf(h4.x, wi0, fmaf(h4.y, wi1, fmaf(h4.z, wi2, fmaf(h4.w, wi3, ai[r]))));
        af[r] = fmaf(h4.x, wf0, fmaf(h4.y, wf1, fmaf(h4.z, wf2, fmaf(h4.w, wf3, af[r]))));
        ag[r] = fmaf(h4.x, wg0, fmaf(h4.y, wg1, fmaf(h4.z, wg2, fmaf(h4.w, wg3, ag[r]))));
        ao[r] = fmaf(h4.x, wo0, fmaf(h4.y, wo1, fmaf(h4.z, wo2, fmaf(h4.w, wo3, ao[r]))));
      }
    }
    __syncthreads();   // all lanes done reading old sh_h

    // pointwise LSTM cell; write new h
    #pragma unroll
    for (int r = 0; r < TM; ++r) {
      float iv = 1.f / (1.f + expf(-ai[r]));
      float fv = 1.f / (1.f + expf(-af[r]));
      float gv = tanhf(ag[r]);
      float ov = 1.f / (1.f + expf(-ao[r]));
      float cn = fmaf(fv, cst[r], iv * gv);
      cst[r] = cn;
      sh_h[r][t] = ov * tanhf(cn);
    }
    __syncthreads();   // new h visible

    // logits = h @ Wa^T + ba, Wa staged in LDS 16 actions at a time
    const int r_lg = t >> 4;
    const int a_lg = t & 15;
    for (int ab = 0; ab < 5; ++ab) {
      int a0 = ab * 16;
      int arows = (a0 + 16 <= NACTS) ? 16 : (NACTS - a0);
      int total4 = arows * HH / 4;
      for (int f4 = t; f4 < total4; f4 += NTH) {
        int idx = f4 * 4;
        int rr = idx >> 9;
        int cc = idx & (HH - 1);
        *reinterpret_cast<float4*>(&sh_buf[rr][cc]) =
            *reinterpret_cast<const float4*>(Wa + (size_t)(a0 + rr) * HH + cc);
      }
      __syncthreads();
      if (a_lg < arows) {
        float acc = 0.f;
        for (int k4 = 0; k4 < HH / 4; ++k4) {
          float4 h4 = *reinterpret_cast<const float4*>(&sh_h[r_lg][k4 * 4]);
          float4 w4 = *reinterpret_cast<const float4*>(&sh_buf[a_lg][k4 * 4]);
          acc = fmaf(h4.x, w4.x, fmaf(h4.y, w4.y, fmaf(h4.z, w4.z, fmaf(h4.w, w4.w, acc))));
        }
        sh_logits[r_lg][a0 + a_lg] = acc + ba[a0 + a_lg];
      }
      __syncthreads();
    }

    // per-row softmax / argmax / entropy / state update (thread r handles row r)
    if (t < TM) {
      const int r = t;
      float m = sh_logits[r][0];
      int am = 0;
      for (int a = 1; a < NACTS; ++a) {
        float v = sh_logits[r][a];
        if (v > m) { m = v; am = a; }   // first-max tie-break, matches jnp.argmax
      }
      float s = 0.f;
      for (int a = 0; a < NACTS; ++a) s += expf(sh_logits[r][a] - m);
      float logZ = m + logf(s);
      float pl = 0.f;
      for (int a = 0; a < NACTS; ++a) {
        float l = sh_logits[r][a];
        pl = fmaf(expf(l - logZ), l, pl);
      }
      float ent = logZ - pl;                       // -sum p*logp
      int stopped = sh_stop[r];
      float lp   = stopped ? 0.f : (sh_logits[r][am] - logZ);
      float entc = stopped ? 0.f : ent;
      int act = stopped ? PAD_TOK : am;
      int grow = row0 + r;
      out[NB + grow * MAXLEN + step] = lp;                       // log_probs
      out[NB + NB * MAXLEN + grow * MAXLEN + step] = (float)act; // message
      sh_ent[r] += entc;
      if (act != PAD_TOK) sh_len[r] += 1;
      if (act == EOS_TOK) sh_stop[r] = 1;
      sh_last[r] = act;
    }
    __syncthreads();   // sh_last/sh_stop ready for next step
  }

  if (t < TM) {
    int r = t, grow = row0 + r;
    float lenf = (float)sh_len[r];
    out[grow] = sh_ent[r] / lenf;                  // entropy (len >= 1 always)
    out[NB + 2 * NB * MAXLEN + grow] = lenf;       // message_len
  }
}

extern "C" void kernel_launch(void* const* d_in, const int* in_sizes, int n_in,
                              void* d_out, int out_size, void* d_ws, size_t ws_size,
                              hipStream_t stream) {
  const float* encoded = (const float*)d_in[0];
  const float* emb     = (const float*)d_in[1];
  const float* W_ih    = (const float*)d_in[2];
  const float* W_hh    = (const float*)d_in[3];
  const float* b_ih    = (const float*)d_in[4];
  const float* b_hh    = (const float*)d_in[5];
  const float* Wc      = (const float*)d_in[6];
  const float* bc      = (const float*)d_in[7];
  const float* Wh      = (const float*)d_in[8];
  const float* bh      = (const float*)d_in[9];
  const float* Wa      = (const float*)d_in[10];
  const float* ba      = (const float*)d_in[11];
  float* out = (float*)d_out;

  float* ws   = (float*)d_ws;
  float* gxa  = ws;                        // 67*2048
  float* whhT = gxa + NVOCAB * G4;         // 512*2048
  float* wcT  = whhT + (size_t)HH * G4;    // 512*512
  float* whT  = wcT + (size_t)HH * HH;     // 512*512  (total ~6.6 MB of ws)

  prep_gxa_kernel<<<(NVOCAB * G4 + 255) / 256, 256, 0, stream>>>(emb, W_ih, b_ih, b_hh, gxa);
  prep_T_kernel<<<(G4 * HH + 255) / 256, 256, 0, stream>>>(W_hh, whhT, G4, HH);
  prep_T_kernel<<<(HH * HH + 255) / 256, 256, 0, stream>>>(Wc, wcT, HH, HH);
  prep_T_kernel<<<(HH * HH + 255) / 256, 256, 0, stream>>>(Wh, whT, HH, HH);

  decode_kernel<<<NB / TM, NTH, 0, stream>>>(encoded, gxa, whhT, wcT, whT,
                                             bc, bh, Wa, ba, out);
}

// Round 2
// 24261.308 us; speedup vs baseline: 1.1654x; 1.1654x over previous
//
#include <hip/hip_runtime.h>
#include <cmath>

// MessageDecoder: 20-step LSTM greedy decoder, B=32768, H=512, 65 actions.
// Round 2: f32 VALU path, restructured for occupancy + clean codegen.
//  - TM=16 rows/block -> 64 acc VGPRs, launch_bounds(512,4), 2 blocks/CU
//  - float4-packed weight layouts (k4-major) -> 4 dwordx4 loads per k4
//  - gates_x table packed as [token][unit][4 gates] -> one float4 gather/row

#define HH      512
#define G4      2048
#define NACTS   65
#define NVOCAB  67
#define MAXLEN  20
#define NB      32768
#define TM      16
#define NTH     512
#define EOS_TOK 0
#define PAD_TOK 65
#define BOS_TOK 66
#define HSTR    516

// gxa4[(a*HH + t)*4 + gate] = emb[a].W_ih[gate*HH+t] + b_ih[c] + b_hh[c]
__global__ void prep_gxa_kernel(const float* __restrict__ emb,
                                const float* __restrict__ W_ih,
                                const float* __restrict__ b_ih,
                                const float* __restrict__ b_hh,
                                float* __restrict__ gxa4) {
  int id = blockIdx.x * blockDim.x + threadIdx.x;
  if (id >= NVOCAB * G4) return;
  int a = id / G4, rem = id - a * G4;
  int t = rem >> 2, gate = rem & 3;
  int c = gate * HH + t;
  const float* e = emb + (size_t)a * HH;
  const float* w = W_ih + (size_t)c * HH;
  float acc = 0.f;
  for (int k = 0; k < HH; ++k) acc = fmaf(e[k], w[k], acc);
  gxa4[id] = acc + b_ih[c] + b_hh[c];
}

// k4-major float4 pack: dst[(k4*cols + c)*4 + j] = src[c*HH + k4*4 + j]
__global__ void prep_w4_kernel(const float* __restrict__ src,
                               float* __restrict__ dst, int cols) {
  int id = blockIdx.x * blockDim.x + threadIdx.x;
  if (id >= cols * HH) return;
  int k4 = id / (cols * 4);
  int rem = id - k4 * cols * 4;
  int c = rem >> 2, j = rem & 3;
  dst[id] = src[(size_t)c * HH + k4 * 4 + j];
}

__global__ __launch_bounds__(NTH, 4)
void decode_kernel(const float* __restrict__ encoded,
                   const float* __restrict__ gxa4,
                   const float* __restrict__ whh4,  // [(k4*2048 + gate*512 + t)*4 + j]
                   const float* __restrict__ wc4,   // [(k4*512 + t)*4 + j]
                   const float* __restrict__ wh4,
                   const float* __restrict__ bc,
                   const float* __restrict__ bh,
                   const float* __restrict__ Wa,    // [65][512] row-major
                   const float* __restrict__ ba,
                   float* __restrict__ out) {
  __shared__ float sh_h[TM][HSTR];
  __shared__ float sh_wa[16][HSTR];
  __shared__ float sh_logits[TM][NACTS + 3];
  __shared__ int   sh_last[TM];
  __shared__ int   sh_stop[TM];
  __shared__ float sh_ent[TM];
  __shared__ int   sh_len[TM];

  const int t = threadIdx.x;
  const int row0 = blockIdx.x * TM;

  // ---- stage encoded[row0:+16][:] into sh_h (reused, then overwritten by h0) ----
  #pragma unroll
  for (int i = 0; i < (TM * HH / 4) / NTH; ++i) {   // 4 float4s per thread
    int f4 = i * NTH + t;
    int idx = f4 * 4;
    int r = idx >> 9;
    int c = idx & (HH - 1);
    *reinterpret_cast<float4*>(&sh_h[r][c]) =
        *reinterpret_cast<const float4*>(encoded + (size_t)(row0 + r) * HH + c);
  }
  if (t < TM) { sh_last[t] = BOS_TOK; sh_stop[t] = 0; sh_ent[t] = 0.f; sh_len[t] = 0; }
  __syncthreads();

  // ---- h0 = enc@Wc^T + bc ; c0 = enc@Wh^T + bh (reference's intentional swap) ----
  float hacc[TM], cacc[TM];
  #pragma unroll
  for (int r = 0; r < TM; ++r) { hacc[r] = 0.f; cacc[r] = 0.f; }
  for (int k4 = 0; k4 < HH / 4; ++k4) {
    float4 wc = *reinterpret_cast<const float4*>(wc4 + ((size_t)k4 * HH + t) * 4);
    float4 wh = *reinterpret_cast<const float4*>(wh4 + ((size_t)k4 * HH + t) * 4);
    #pragma unroll
    for (int r = 0; r < TM; ++r) {
      float4 e = *reinterpret_cast<const float4*>(&sh_h[r][k4 * 4]);
      hacc[r] = fmaf(e.x, wc.x, fmaf(e.y, wc.y, fmaf(e.z, wc.z, fmaf(e.w, wc.w, hacc[r]))));
      cacc[r] = fmaf(e.x, wh.x, fmaf(e.y, wh.y, fmaf(e.z, wh.z, fmaf(e.w, wh.w, cacc[r]))));
    }
  }
  __syncthreads();   // done reading enc from sh_h
  float cst[TM];
  {
    float bcv = bc[t], bhv = bh[t];
    #pragma unroll
    for (int r = 0; r < TM; ++r) {
      sh_h[r][t] = hacc[r] + bcv;
      cst[r] = cacc[r] + bhv;
    }
  }
  __syncthreads();

  // ---- 20 decode steps ----
  for (int step = 0; step < MAXLEN; ++step) {
    // x-side gates: one float4 gather per row (i,f,g,o interleaved)
    float ai[TM], af[TM], ag[TM], ao[TM];
    #pragma unroll
    for (int r = 0; r < TM; ++r) {
      float4 g = *reinterpret_cast<const float4*>(gxa4 + ((size_t)sh_last[r] * HH + t) * 4);
      ai[r] = g.x; af[r] = g.y; ag[r] = g.z; ao[r] = g.w;
    }
    // gates += h @ W_hh^T
    for (int k4 = 0; k4 < HH / 4; ++k4) {
      const float* wb = whh4 + ((size_t)k4 * G4 + t) * 4;
      float4 wi = *reinterpret_cast<const float4*>(wb);
      float4 wf = *reinterpret_cast<const float4*>(wb + 4 * HH);
      float4 wg = *reinterpret_cast<const float4*>(wb + 8 * HH);
      float4 wo = *reinterpret_cast<const float4*>(wb + 12 * HH);
      #pragma unroll
      for (int r = 0; r < TM; ++r) {
        float4 h4 = *reinterpret_cast<const float4*>(&sh_h[r][k4 * 4]);
        ai[r] = fmaf(h4.x, wi.x, fmaf(h4.y, wi.y, fmaf(h4.z, wi.z, fmaf(h4.w, wi.w, ai[r]))));
        af[r] = fmaf(h4.x, wf.x, fmaf(h4.y, wf.y, fmaf(h4.z, wf.z, fmaf(h4.w, wf.w, af[r]))));
        ag[r] = fmaf(h4.x, wg.x, fmaf(h4.y, wg.y, fmaf(h4.z, wg.z, fmaf(h4.w, wg.w, ag[r]))));
        ao[r] = fmaf(h4.x, wo.x, fmaf(h4.y, wo.y, fmaf(h4.z, wo.z, fmaf(h4.w, wo.w, ao[r]))));
      }
    }
    __syncthreads();   // all lanes done reading old sh_h

    // pointwise LSTM cell; write new h
    #pragma unroll
    for (int r = 0; r < TM; ++r) {
      float iv = 1.f / (1.f + expf(-ai[r]));
      float fv = 1.f / (1.f + expf(-af[r]));
      float gv = tanhf(ag[r]);
      float ov = 1.f / (1.f + expf(-ao[r]));
      float cn = fmaf(fv, cst[r], iv * gv);
      cst[r] = cn;
      sh_h[r][t] = ov * tanhf(cn);
    }
    __syncthreads();   // new h visible

    // logits = h @ Wa^T + ba ; Wa staged 16 actions/pass
    const int r_lg = t >> 5;     // 0..15
    const int a_lg = t & 31;     // active if < arows
    for (int ab = 0; ab < 5; ++ab) {
      int a0 = ab * 16;
      int arows = (a0 + 16 <= NACTS) ? 16 : (NACTS - a0);
      int total4 = arows * HH / 4;
      for (int f4 = t; f4 < total4; f4 += NTH) {
        int idx = f4 * 4;
        int rr = idx >> 9;
        int cc = idx & (HH - 1);
        *reinterpret_cast<float4*>(&sh_wa[rr][cc]) =
            *reinterpret_cast<const float4*>(Wa + (size_t)(a0 + rr) * HH + cc);
      }
      __syncthreads();
      if (a_lg < arows) {
        float acc = 0.f;
        for (int k4 = 0; k4 < HH / 4; ++k4) {
          float4 h4 = *reinterpret_cast<const float4*>(&sh_h[r_lg][k4 * 4]);
          float4 w4 = *reinterpret_cast<const float4*>(&sh_wa[a_lg][k4 * 4]);
          acc = fmaf(h4.x, w4.x, fmaf(h4.y, w4.y, fmaf(h4.z, w4.z, fmaf(h4.w, w4.w, acc))));
        }
        sh_logits[r_lg][a0 + a_lg] = acc + ba[a0 + a_lg];
      }
      __syncthreads();
    }

    // per-row softmax / argmax / entropy / state update
    if (t < TM) {
      const int r = t;
      float m = sh_logits[r][0];
      int am = 0;
      for (int a = 1; a < NACTS; ++a) {
        float v = sh_logits[r][a];
        if (v > m) { m = v; am = a; }
      }
      float s = 0.f;
      for (int a = 0; a < NACTS; ++a) s += expf(sh_logits[r][a] - m);
      float logZ = m + logf(s);
      float pl = 0.f;
      for (int a = 0; a < NACTS; ++a) {
        float l = sh_logits[r][a];
        pl = fmaf(expf(l - logZ), l, pl);
      }
      float ent = logZ - pl;
      int stopped = sh_stop[r];
      float lp   = stopped ? 0.f : (sh_logits[r][am] - logZ);
      float entc = stopped ? 0.f : ent;
      int act = stopped ? PAD_TOK : am;
      int grow = row0 + r;
      out[NB + grow * MAXLEN + step] = lp;                        // log_probs
      out[NB + NB * MAXLEN + grow * MAXLEN + step] = (float)act;  // message
      sh_ent[r] += entc;
      if (act != PAD_TOK) sh_len[r] += 1;
      if (act == EOS_TOK) sh_stop[r] = 1;
      sh_last[r] = act;
    }
    __syncthreads();
  }

  if (t < TM) {
    int r = t, grow = row0 + r;
    float lenf = (float)sh_len[r];
    out[grow] = sh_ent[r] / lenf;                   // entropy
    out[NB + 2 * NB * MAXLEN + grow] = lenf;        // message_len
  }
}

extern "C" void kernel_launch(void* const* d_in, const int* in_sizes, int n_in,
                              void* d_out, int out_size, void* d_ws, size_t ws_size,
                              hipStream_t stream) {
  const float* encoded = (const float*)d_in[0];
  const float* emb     = (const float*)d_in[1];
  const float* W_ih    = (const float*)d_in[2];
  const float* W_hh    = (const float*)d_in[3];
  const float* b_ih    = (const float*)d_in[4];
  const float* b_hh    = (const float*)d_in[5];
  const float* Wc      = (const float*)d_in[6];
  const float* bc      = (const float*)d_in[7];
  const float* Wh      = (const float*)d_in[8];
  const float* bh      = (const float*)d_in[9];
  const float* Wa      = (const float*)d_in[10];
  const float* ba      = (const float*)d_in[11];
  float* out = (float*)d_out;

  float* ws   = (float*)d_ws;
  float* gxa4 = ws;                         // 67*2048
  float* whh4 = gxa4 + NVOCAB * G4;         // 512*2048 (k4-major packed)
  float* wc4  = whh4 + (size_t)HH * G4;     // 512*512
  float* wh4  = wc4 + (size_t)HH * HH;      // 512*512

  prep_gxa_kernel<<<(NVOCAB * G4 + 255) / 256, 256, 0, stream>>>(emb, W_ih, b_ih, b_hh, gxa4);
  prep_w4_kernel<<<(G4 * HH + 255) / 256, 256, 0, stream>>>(W_hh, whh4, G4);
  prep_w4_kernel<<<(HH * HH + 255) / 256, 256, 0, stream>>>(Wc, wc4, HH);
  prep_w4_kernel<<<(HH * HH + 255) / 256, 256, 0, stream>>>(Wh, wh4, HH);

  decode_kernel<<<NB / TM, NTH, 0, stream>>>(encoded, gxa4, whh4, wc4, wh4,
                                             bc, bh, Wa, ba, out);
}

// Round 7
// 21043.871 us; speedup vs baseline: 1.3436x; 1.1529x over previous
//
#include <hip/hip_runtime.h>
#include <cmath>

// MessageDecoder: 20-step LSTM greedy decoder, B=32768, H=512, 65 actions.
// Round 7: bitwise-r2 f32 arithmetic (the only class proven to match the
// reference's argmax decisions), restructured for VALU throughput:
//  - thread owns 2 cols (t, t+256): 512 FMA per k4 vs 16 LDS broadcast reads
//  - 256-thread blocks, TM=16, launch_bounds(256,2): no register starvation
//  - per-output-element fmaf chains identical to r2 -> bitwise-identical output

#define HH      512
#define G4      2048
#define NACTS   65
#define NVOCAB  67
#define MAXLEN  20
#define NB      32768
#define TM      16
#define NTH     256
#define EOS_TOK 0
#define PAD_TOK 65
#define BOS_TOK 66
#define HSTR    516

// gxa4[(a*HH + t)*4 + gate] = emb[a].W_ih[gate*HH+t] + b_ih[c] + b_hh[c]
__global__ void prep_gxa_kernel(const float* __restrict__ emb,
                                const float* __restrict__ W_ih,
                                const float* __restrict__ b_ih,
                                const float* __restrict__ b_hh,
                                float* __restrict__ gxa4) {
  int id = blockIdx.x * blockDim.x + threadIdx.x;
  if (id >= NVOCAB * G4) return;
  int a = id / G4, rem = id - a * G4;
  int t = rem >> 2, gate = rem & 3;
  int c = gate * HH + t;
  const float* e = emb + (size_t)a * HH;
  const float* w = W_ih + (size_t)c * HH;
  float acc = 0.f;
  for (int k = 0; k < HH; ++k) acc = fmaf(e[k], w[k], acc);
  gxa4[id] = acc + b_ih[c] + b_hh[c];
}

// k4-major float4 pack: dst[(k4*cols + c)*4 + j] = src[c*HH + k4*4 + j]
__global__ void prep_w4_kernel(const float* __restrict__ src,
                               float* __restrict__ dst, int cols) {
  int id = blockIdx.x * blockDim.x + threadIdx.x;
  if (id >= cols * HH) return;
  int k4 = id / (cols * 4);
  int rem = id - k4 * cols * 4;
  int c = rem >> 2, j = rem & 3;
  dst[id] = src[(size_t)c * HH + k4 * 4 + j];
}

__global__ void ws_sentinel_kernel(float* out) {
  out[threadIdx.x] = 123000.f;
}

// acc = h.w*w.w -> h.z*w.z -> h.y*w.y -> h.x*w.x nested (r2's exact chain)
#define FMA4(acc, h, wv) \
  acc = fmaf((h).x, (wv).x, fmaf((h).y, (wv).y, fmaf((h).z, (wv).z, fmaf((h).w, (wv).w, (acc)))))

__global__ __launch_bounds__(NTH, 2)
void decode_kernel(const float* __restrict__ encoded,
                   const float* __restrict__ gxa4,
                   const float* __restrict__ whh4,  // [(k4*2048 + gate*512 + c)*4 + j]
                   const float* __restrict__ wc4,   // [(k4*512 + c)*4 + j]
                   const float* __restrict__ wh4,
                   const float* __restrict__ bc,
                   const float* __restrict__ bh,
                   const float* __restrict__ Wa,    // [65][512] row-major
                   const float* __restrict__ ba,
                   float* __restrict__ out) {
  __shared__ float sh_h[TM][HSTR];
  __shared__ float sh_wa[16][HSTR];
  __shared__ float sh_logits[TM][NACTS + 3];
  __shared__ int   sh_last[TM];
  __shared__ int   sh_stop[TM];
  __shared__ float sh_ent[TM];
  __shared__ int   sh_len[TM];

  const int t = threadIdx.x;               // owns cols t and t+256
  const int row0 = blockIdx.x * TM;

  // ---- stage encoded[row0:+16][:] into sh_h (coalesced float4) ----
  #pragma unroll
  for (int i = 0; i < (TM * HH / 4) / NTH; ++i) {   // 8 float4s per thread
    int f4 = i * NTH + t;
    int idx = f4 * 4;
    int r = idx >> 9;
    int c = idx & (HH - 1);
    *reinterpret_cast<float4*>(&sh_h[r][c]) =
        *reinterpret_cast<const float4*>(encoded + (size_t)(row0 + r) * HH + c);
  }
  if (t < TM) { sh_last[t] = BOS_TOK; sh_stop[t] = 0; sh_ent[t] = 0.f; sh_len[t] = 0; }
  __syncthreads();

  // ---- h0 = enc@Wc^T + bc ; c0 = enc@Wh^T + bh (reference's intentional swap) ----
  float hacc[2][TM], cacc[2][TM];
  #pragma unroll
  for (int j = 0; j < 2; ++j)
    #pragma unroll
    for (int r = 0; r < TM; ++r) { hacc[j][r] = 0.f; cacc[j][r] = 0.f; }
  #pragma unroll 1
  for (int k4 = 0; k4 < HH / 4; ++k4) {
    const float* wcb = wc4 + ((size_t)k4 * HH + t) * 4;
    const float* whb = wh4 + ((size_t)k4 * HH + t) * 4;
    float4 wc0 = *reinterpret_cast<const float4*>(wcb);
    float4 wc1 = *reinterpret_cast<const float4*>(wcb + 1024);
    float4 wh0 = *reinterpret_cast<const float4*>(whb);
    float4 wh1 = *reinterpret_cast<const float4*>(whb + 1024);
    #pragma unroll
    for (int r = 0; r < TM; ++r) {
      float4 e = *reinterpret_cast<const float4*>(&sh_h[r][k4 * 4]);
      FMA4(hacc[0][r], e, wc0);
      FMA4(hacc[1][r], e, wc1);
      FMA4(cacc[0][r], e, wh0);
      FMA4(cacc[1][r], e, wh1);
    }
  }
  __syncthreads();   // done reading enc from sh_h
  float cst[2][TM];
  {
    float bc0 = bc[t], bc1 = bc[t + 256];
    float bh0 = bh[t], bh1 = bh[t + 256];
    #pragma unroll
    for (int r = 0; r < TM; ++r) {
      sh_h[r][t] = hacc[0][r] + bc0;
      sh_h[r][t + 256] = hacc[1][r] + bc1;
      cst[0][r] = cacc[0][r] + bh0;
      cst[1][r] = cacc[1][r] + bh1;
    }
  }
  __syncthreads();

  // ---- 20 decode steps ----
  for (int step = 0; step < MAXLEN; ++step) {
    // x-side gates: two float4 gathers per row (i,f,g,o interleaved)
    float ai[2][TM], af[2][TM], ag[2][TM], ao[2][TM];
    #pragma unroll
    for (int r = 0; r < TM; ++r) {
      const float* g0 = gxa4 + ((size_t)sh_last[r] * HH + t) * 4;
      float4 ga = *reinterpret_cast<const float4*>(g0);
      float4 gb = *reinterpret_cast<const float4*>(g0 + 1024);
      ai[0][r] = ga.x; af[0][r] = ga.y; ag[0][r] = ga.z; ao[0][r] = ga.w;
      ai[1][r] = gb.x; af[1][r] = gb.y; ag[1][r] = gb.z; ao[1][r] = gb.w;
    }
    // gates += h @ W_hh^T  (512 FMA per k4 per thread, 16 LDS broadcasts)
    #pragma unroll 1
    for (int k4 = 0; k4 < HH / 4; ++k4) {
      const float* wb = whh4 + (size_t)k4 * (G4 * 4) + t * 4;
      float4 wi0 = *reinterpret_cast<const float4*>(wb);
      float4 wf0 = *reinterpret_cast<const float4*>(wb + 2048);
      float4 wg0 = *reinterpret_cast<const float4*>(wb + 4096);
      float4 wo0 = *reinterpret_cast<const float4*>(wb + 6144);
      float4 wi1 = *reinterpret_cast<const float4*>(wb + 1024);
      float4 wf1 = *reinterpret_cast<const float4*>(wb + 2048 + 1024);
      float4 wg1 = *reinterpret_cast<const float4*>(wb + 4096 + 1024);
      float4 wo1 = *reinterpret_cast<const float4*>(wb + 6144 + 1024);
      #pragma unroll
      for (int r = 0; r < TM; ++r) {
        float4 h4 = *reinterpret_cast<const float4*>(&sh_h[r][k4 * 4]);
        FMA4(ai[0][r], h4, wi0);
        FMA4(af[0][r], h4, wf0);
        FMA4(ag[0][r], h4, wg0);
        FMA4(ao[0][r], h4, wo0);
        FMA4(ai[1][r], h4, wi1);
        FMA4(af[1][r], h4, wf1);
        FMA4(ag[1][r], h4, wg1);
        FMA4(ao[1][r], h4, wo1);
      }
    }
    __syncthreads();   // all lanes done reading old sh_h

    // pointwise LSTM cell; write new h  (identical arithmetic to r2)
    #pragma unroll
    for (int j = 0; j < 2; ++j) {
      int col = t + j * 256;
      #pragma unroll
      for (int r = 0; r < TM; ++r) {
        float iv = 1.f / (1.f + expf(-ai[j][r]));
        float fv = 1.f / (1.f + expf(-af[j][r]));
        float gv = tanhf(ag[j][r]);
        float ov = 1.f / (1.f + expf(-ao[j][r]));
        float cn = fmaf(fv, cst[j][r], iv * gv);
        cst[j][r] = cn;
        sh_h[r][col] = ov * tanhf(cn);
      }
    }
    __syncthreads();   // new h visible

    // logits = h @ Wa^T + ba ; Wa staged 16 actions/pass (r2 chain exactly)
    const int r_lg = t >> 4;     // 0..15
    const int a_lg = t & 15;     // 0..15
    for (int ab = 0; ab < 5; ++ab) {
      int a0 = ab * 16;
      int arows = (a0 + 16 <= NACTS) ? 16 : (NACTS - a0);
      int total4 = arows * HH / 4;
      for (int f4 = t; f4 < total4; f4 += NTH) {
        int idx = f4 * 4;
        int rr = idx >> 9;
        int cc = idx & (HH - 1);
        *reinterpret_cast<float4*>(&sh_wa[rr][cc]) =
            *reinterpret_cast<const float4*>(Wa + (size_t)(a0 + rr) * HH + cc);
      }
      __syncthreads();
      if (a_lg < arows) {
        float acc = 0.f;
        #pragma unroll 1
        for (int k4 = 0; k4 < HH / 4; ++k4) {
          float4 h4 = *reinterpret_cast<const float4*>(&sh_h[r_lg][k4 * 4]);
          float4 w4 = *reinterpret_cast<const float4*>(&sh_wa[a_lg][k4 * 4]);
          FMA4(acc, h4, w4);
        }
        sh_logits[r_lg][a0 + a_lg] = acc + ba[a0 + a_lg];
      }
      __syncthreads();
    }

    // per-row softmax / argmax / entropy / state update (r2 verbatim)
    if (t < TM) {
      const int r = t;
      float m = sh_logits[r][0];
      int am = 0;
      #pragma unroll 1
      for (int a = 1; a < NACTS; ++a) {
        float v = sh_logits[r][a];
        if (v > m) { m = v; am = a; }
      }
      float s = 0.f;
      #pragma unroll 1
      for (int a = 0; a < NACTS; ++a) s += expf(sh_logits[r][a] - m);
      float logZ = m + logf(s);
      float pl = 0.f;
      #pragma unroll 1
      for (int a = 0; a < NACTS; ++a) {
        float l = sh_logits[r][a];
        pl = fmaf(expf(l - logZ), l, pl);
      }
      float ent = logZ - pl;
      int stopped = sh_stop[r];
      float lp   = stopped ? 0.f : (sh_logits[r][am] - logZ);
      float entc = stopped ? 0.f : ent;
      int act = stopped ? PAD_TOK : am;
      int grow = row0 + r;
      out[NB + (size_t)grow * MAXLEN + step] = lp;                        // log_probs
      out[NB + (size_t)NB * MAXLEN + (size_t)grow * MAXLEN + step] = (float)act;  // message
      sh_ent[r] += entc;
      if (act != PAD_TOK) sh_len[r] += 1;
      if (act == EOS_TOK) sh_stop[r] = 1;
      sh_last[r] = act;
    }
    __syncthreads();
  }

  if (t < TM) {
    int r = t, grow = row0 + r;
    float lenf = (float)sh_len[r];
    out[grow] = sh_ent[r] / lenf;                           // entropy
    out[NB + 2 * (size_t)NB * MAXLEN + grow] = lenf;        // message_len
  }
}

extern "C" void kernel_launch(void* const* d_in, const int* in_sizes, int n_in,
                              void* d_out, int out_size, void* d_ws, size_t ws_size,
                              hipStream_t stream) {
  const float* encoded = (const float*)d_in[0];
  const float* emb     = (const float*)d_in[1];
  const float* W_ih    = (const float*)d_in[2];
  const float* W_hh    = (const float*)d_in[3];
  const float* b_ih    = (const float*)d_in[4];
  const float* b_hh    = (const float*)d_in[5];
  const float* Wc      = (const float*)d_in[6];
  const float* bc      = (const float*)d_in[7];
  const float* Wh      = (const float*)d_in[8];
  const float* bh      = (const float*)d_in[9];
  const float* Wa      = (const float*)d_in[10];
  const float* ba      = (const float*)d_in[11];
  float* out = (float*)d_out;

  size_t need = ((size_t)NVOCAB * G4 + (size_t)G4 * HH + 2 * (size_t)HH * HH) * 4;
  if (ws_size < need) {
    ws_sentinel_kernel<<<1, 64, 0, stream>>>(out);
    return;
  }

  float* ws   = (float*)d_ws;
  float* gxa4 = ws;                         // 67*2048
  float* whh4 = gxa4 + NVOCAB * G4;         // 2048*512 (k4-major packed)
  float* wc4  = whh4 + (size_t)HH * G4;     // 512*512
  float* wh4  = wc4 + (size_t)HH * HH;      // 512*512

  prep_gxa_kernel<<<(NVOCAB * G4 + 255) / 256, 256, 0, stream>>>(emb, W_ih, b_ih, b_hh, gxa4);
  prep_w4_kernel<<<(G4 * HH + 255) / 256, 256, 0, stream>>>(W_hh, whh4, G4);
  prep_w4_kernel<<<(HH * HH + 255) / 256, 256, 0, stream>>>(Wc, wc4, HH);
  prep_w4_kernel<<<(HH * HH + 255) / 256, 256, 0, stream>>>(Wh, wh4, HH);

  decode_kernel<<<NB / TM, NTH, 0, stream>>>(encoded, gxa4, whh4, wc4, wh4,
                                             bc, bh, Wa, ba, out);
}